// Round 5
// baseline (405.024 us; speedup 1.0000x reference)
//
#include <hip/hip_runtime.h>
#include <math.h>
#include <stdint.h>

// Problem constants
#define LL 768
#define DIN 384
#define HH 12
#define NLIN 1080          // 192*3 + 144*2 + 216
#define WC_HALF 0.11785113019775792f   // 0.5*sqrt(2/36)
#define C_SQU 0.25f

// Workspace layout (float units)
#define OFF_LIN    0u          // 829440
#define OFF_V3G    829440u     // 165888
#define OFF_QBH    995328u     // 147456 (bf16 768*12*32)
#define OFF_KBH    1142784u    // 147456
#define OFF_QBL    1290240u    // 147456
#define OFF_KBL    1437696u    // 147456
#define OFF_WZ     1585152u    // 1024   (bf16 4*64*8)
#define OFF_SQWH   1586176u    // 9216
#define OFF_SKWH   1595392u    // 9216
#define OFF_SX     1604608u    // 7077888 fp32 (part[] aliases here later)
#define OFF_O1     8682496u    // 1179648
#define OFF_O2     9862144u    // 147456
#define OFF_O3     10009600u   // 165888
// end: 10175488 floats = 40.7 MB

typedef __attribute__((ext_vector_type(8))) short short8v;
typedef __attribute__((ext_vector_type(4))) float float4v;

__device__ __forceinline__ ushort f2bu(float f) {
    union { float f; uint32_t u; } v; v.f = f;
    uint32_t r = (v.u + 0x7FFFu + ((v.u >> 16) & 1u)) >> 16;
    return (ushort)r;
}
__device__ __forceinline__ float bu2f(ushort u) {
    union { uint32_t u; float f; } v; v.u = ((uint32_t)u) << 16; return v.f;
}

// ---------------------------------------------------------------------------
// Kernel 1: lin = s @ [Wq1|Wk1|Wv1|Wq2|Wk2|Wv3]   ([768,384]@[384,1080])
// ---------------------------------------------------------------------------
__global__ __launch_bounds__(256) void gemm_lin_kernel(
    const float* __restrict__ s,
    const float* __restrict__ Wq1, const float* __restrict__ Wk1,
    const float* __restrict__ Wv1, const float* __restrict__ Wq2,
    const float* __restrict__ Wk2, const float* __restrict__ Wv3,
    float* __restrict__ lin)
{
    const int n0 = blockIdx.x * 64;
    const int i0 = blockIdx.y * 64;
    const int tid = threadIdx.x;
    __shared__ float sT[64][17];
    __shared__ float wT[16][65];
    const int tc = tid & 15, tr = tid >> 4;
    float acc[4][4] = {};
    for (int k0 = 0; k0 < DIN; k0 += 16) {
        __syncthreads();
        for (int idx = tid; idx < 1024; idx += 256) {
            int r = idx >> 4, kk = idx & 15;
            sT[r][kk] = s[(size_t)(i0 + r) * DIN + k0 + kk];
        }
        for (int idx = tid; idx < 1024; idx += 256) {
            int kk = idx >> 6, c = idx & 63;
            int col = n0 + c;
            float v = 0.f;
            if (col < NLIN) {
                const float* W; int nout, cc2;
                if      (col < 192) { W = Wq1; nout = 192; cc2 = col; }
                else if (col < 384) { W = Wk1; nout = 192; cc2 = col - 192; }
                else if (col < 576) { W = Wv1; nout = 192; cc2 = col - 384; }
                else if (col < 720) { W = Wq2; nout = 144; cc2 = col - 576; }
                else if (col < 864) { W = Wk2; nout = 144; cc2 = col - 720; }
                else                { W = Wv3; nout = 216; cc2 = col - 864; }
                v = W[(size_t)(k0 + kk) * nout + cc2];
            }
            wT[kk][c] = v;
        }
        __syncthreads();
        #pragma unroll
        for (int kk = 0; kk < 16; ++kk) {
            float a[4], b[4];
            #pragma unroll
            for (int r = 0; r < 4; ++r) a[r] = sT[tr * 4 + r][kk];
            #pragma unroll
            for (int c = 0; c < 4; ++c) b[c] = wT[kk][tc * 4 + c];
            #pragma unroll
            for (int r = 0; r < 4; ++r)
                #pragma unroll
                for (int c = 0; c < 4; ++c) acc[r][c] += a[r] * b[c];
        }
    }
    for (int r = 0; r < 4; ++r)
        for (int c = 0; c < 4; ++c) {
            int col = n0 + tc * 4 + c;
            if (col < NLIN)
                lin[(size_t)(i0 + tr * 4 + r) * NLIN + col] = acc[r][c];
        }
}

// ---------------------------------------------------------------------------
// Kernel 2: transforms -> v3g ; hi/lo bf16 bundles (qbh/qbl, kbh/kbl);
// fp32 sqwh = wh*sq, skwh = wh*sk ; Wz A-frag pack.
// dot(qb,kb) = C_SQU*qk + 2wh*cross ; score = dot - sqwh[i] - skwh[j].
// ---------------------------------------------------------------------------
__global__ __launch_bounds__(192) void transform_kernel(
    const float* __restrict__ lin, const float* __restrict__ rot,
    const float* __restrict__ trans, const float* __restrict__ gamma,
    const float* __restrict__ Wz,
    float* __restrict__ v3g,
    ushort* __restrict__ qbh, ushort* __restrict__ qbl,
    ushort* __restrict__ kbh, ushort* __restrict__ kbl,
    ushort* __restrict__ wzpack,
    float* __restrict__ sqwh, float* __restrict__ skwh)
{
    const int l = blockIdx.x;
    const int tid = threadIdx.x;
    __shared__ float q2s[144], k2s[144], sqp[48], skp[48];
    __shared__ float whs[12];
    __shared__ float R[9], T[3];
    if (tid < 9) R[tid] = rot[l * 9 + tid];
    if (tid >= 9 && tid < 12) T[tid - 9] = trans[l * 3 + tid - 9];
    __syncthreads();
    if (tid < 48) {
        const float* x = &lin[(size_t)l * NLIN + 576 + tid * 3];
        float x0 = x[0], x1 = x[1], x2 = x[2], ss = 0.f;
        #pragma unroll
        for (int i2 = 0; i2 < 3; ++i2) {
            float v = R[i2*3+0]*x0 + R[i2*3+1]*x1 + R[i2*3+2]*x2 + T[i2];
            q2s[tid * 3 + i2] = v; ss += v * v;
        }
        sqp[tid] = ss;
    } else if (tid < 96) {
        int t2 = tid - 48;
        const float* x = &lin[(size_t)l * NLIN + 720 + t2 * 3];
        float x0 = x[0], x1 = x[1], x2 = x[2], ss = 0.f;
        #pragma unroll
        for (int i2 = 0; i2 < 3; ++i2) {
            float v = R[i2*3+0]*x0 + R[i2*3+1]*x1 + R[i2*3+2]*x2 + T[i2];
            k2s[t2 * 3 + i2] = v; ss += v * v;
        }
        skp[t2] = ss;
    } else if (tid < 168) {
        int t2 = tid - 96;
        const float* x = &lin[(size_t)l * NLIN + 864 + t2 * 3];
        float x0 = x[0], x1 = x[1], x2 = x[2];
        #pragma unroll
        for (int i2 = 0; i2 < 3; ++i2) {
            float v = R[i2*3+0]*x0 + R[i2*3+1]*x1 + R[i2*3+2]*x2 + T[i2];
            v3g[(size_t)l * 216 + t2 * 3 + i2] = v;
        }
    }
    __syncthreads();
    if (tid < 12) {
        float sq = sqp[tid*4] + sqp[tid*4+1] + sqp[tid*4+2] + sqp[tid*4+3];
        float sk = skp[tid*4] + skp[tid*4+1] + skp[tid*4+2] + skp[tid*4+3];
        float w = logf(1.0f + expf(gamma[tid])) * WC_HALF;
        whs[tid] = w;
        sqwh[l * 12 + tid] = w * sq;   // fp32, exact path
        skwh[l * 12 + tid] = w * sk;
    }
    __syncthreads();
    for (int idx = tid; idx < 384; idx += 192) {
        int h = idx >> 5, k = idx & 31;
        float qv, kv;
        if (k < 16) {
            qv = lin[(size_t)l * NLIN + h * 16 + k];
            kv = C_SQU * lin[(size_t)l * NLIN + 192 + h * 16 + k];
        } else if (k < 28) {
            int u = k - 16;
            qv = q2s[h * 12 + u];
            kv = 2.0f * whs[h] * k2s[h * 12 + u];
        } else { qv = 0.0f; kv = 0.0f; }
        size_t base = (size_t)l * 384 + idx;
        ushort qh = f2bu(qv), kh = f2bu(kv);
        qbh[base] = qh; qbl[base] = f2bu(qv - bu2f(qh));
        kbh[base] = kh; kbl[base] = f2bu(kv - bu2f(kh));
    }
    if (l == 0) {  // wzpack[kb][lane][e] = Wz[kb*32+(lane>>4)*8+e][lane&15]
        for (int idx = tid; idx < 2048; idx += 192) {
            int kb = idx >> 9, lane = (idx >> 3) & 63, e = idx & 7;
            int d = kb * 32 + (lane >> 4) * 8 + e, h = lane & 15;
            wzpack[idx] = (h < 12) ? f2bu(Wz[d * 12 + h]) : (ushort)0;
        }
    }
}

// ---------------------------------------------------------------------------
// Kernel 3: sx[i][h][j] = hi/lo-dot(qb,kb) - sqwh[i,h] - skwh[j,h] (fp32)
// ---------------------------------------------------------------------------
__global__ __launch_bounds__(256) void sextra_kernel(
    const ushort* __restrict__ qbh, const ushort* __restrict__ qbl,
    const ushort* __restrict__ kbh, const ushort* __restrict__ kbl,
    const float* __restrict__ sqwh, const float* __restrict__ skwh,
    float* __restrict__ sx)
{
    const int tid = threadIdx.x;
    const int wv = tid >> 6, lane = tid & 63, lm = lane & 15, g = lane >> 4;
    const int i0 = blockIdx.x * 16;
    const int jb = blockIdx.y * 64 + wv * 16;
    for (int h = 0; h < 12; ++h) {
        size_t qoff = ((size_t)(i0 + lm) * 12 + h) * 32 + g * 8;
        size_t koff = ((size_t)(jb + lm) * 12 + h) * 32 + g * 8;
        short8v ah = *(const short8v*)(qbh + qoff);
        short8v al = *(const short8v*)(qbl + qoff);
        short8v bh = *(const short8v*)(kbh + koff);
        short8v bl = *(const short8v*)(kbl + koff);
        float4v c = {0.f, 0.f, 0.f, 0.f};
        c = __builtin_amdgcn_mfma_f32_16x16x32_bf16(ah, bh, c, 0, 0, 0);
        c = __builtin_amdgcn_mfma_f32_16x16x32_bf16(ah, bl, c, 0, 0, 0);
        c = __builtin_amdgcn_mfma_f32_16x16x32_bf16(al, bh, c, 0, 0, 0);
        float skv = skwh[(jb + lm) * 12 + h];
        #pragma unroll
        for (int r = 0; r < 4; ++r) {
            int ii = i0 + g * 4 + r;
            sx[((size_t)ii * 12 + h) * 768 + jb + lm] =
                c[r] - sqwh[ii * 12 + h] - skv;
        }
    }
}

// ---------------------------------------------------------------------------
// Kernel 4: fused attention. One block per query row i.
// zT swizzle mask is ((d>>2)&3)<<4  — stays inside the 64-B row (bijective).
// ---------------------------------------------------------------------------
__global__ __launch_bounds__(256) void attn_kernel(
    const float* __restrict__ z, const float* __restrict__ lin,
    const float* __restrict__ v3g, const float* __restrict__ sx,
    const ushort* __restrict__ wzp,
    const float* __restrict__ rot, const float* __restrict__ trans,
    float* __restrict__ o1, float* __restrict__ o2, float* __restrict__ o3l)
{
    const int i = blockIdx.x, tid = threadIdx.x;
    const int wv = tid >> 6, lane = tid & 63, lm = lane & 15, g = lane >> 4;
    __shared__ __attribute__((aligned(16))) char zrow[2][32 * 256]; // [j][d] bf16, swz ^((j&7)<<4)
    __shared__ __attribute__((aligned(16))) char zT[2][128 * 64];   // [d][j] bf16, swz ^(((d>>2)&3)<<4)
    __shared__ __attribute__((aligned(16))) char attbh[16 * 80];    // hi bf16 [h][j]
    __shared__ __attribute__((aligned(16))) char attbl[16 * 80];    // lo bf16 [h][j]
    __shared__ float attf[16][33];                                  // fp32 [h][j]
    __shared__ float o3s[216];

    short8v wzf[4];
    #pragma unroll
    for (int kb = 0; kb < 4; ++kb)
        wzf[kb] = *(const short8v*)(wzp + (kb * 64 + lane) * 8);

    const float4* zsrc = (const float4*)(z + (size_t)i * (LL * 128));
    float4 zreg[4];
    #pragma unroll
    for (int s = 0; s < 4; ++s) zreg[s] = zsrc[s * 256 + tid];
    int p = 0;
    #pragma unroll
    for (int s = 0; s < 4; ++s) {
        int k4 = s * 256 + tid, j = k4 >> 5, d0 = (k4 & 31) * 4;
        float4 v = zreg[s];
        ushort b0 = f2bu(v.x), b1 = f2bu(v.y), b2 = f2bu(v.z), b3 = f2bu(v.w);
        uint32_t lo = b0 | ((uint32_t)b1 << 16), hi = b2 | ((uint32_t)b3 << 16);
        *(uint64_t*)(&zrow[0][j * 256 + ((d0 * 2) ^ ((j & 7) << 4))]) =
            (uint64_t)lo | ((uint64_t)hi << 32);
        ushort bs[4] = {b0, b1, b2, b3};
        #pragma unroll
        for (int m = 0; m < 4; ++m) {
            int d = d0 + m;
            *(ushort*)(&zT[0][d * 64 + ((j * 2) ^ (((d >> 2) & 3) << 4))]) = bs[m];
        }
    }
    __syncthreads();

    float4v acc1[2] = {{0.f,0.f,0.f,0.f}, {0.f,0.f,0.f,0.f}};
    float acc2 = 0.f, acc3 = 0.f;
    const int h2 = tid >> 4;       // o2 head (tid<192)
    const int h3 = tid / 18;       // o3 head (tid<216)

    for (int t = 0; t < 24; ++t) {
        const int j0 = t * 32;
        if (t < 23) {
            #pragma unroll
            for (int s = 0; s < 4; ++s)
                zreg[s] = zsrc[(size_t)(t + 1) * 1024 + s * 256 + tid];
        }
        // ---- phase A: waves 0/1 produce att tile ----
        if (wv < 2) {
            const int j = wv * 16 + lm;
            float4v bias = {0.f, 0.f, 0.f, 0.f};
            #pragma unroll
            for (int kb = 0; kb < 4; ++kb) {
                short8v bz = *(const short8v*)(
                    &zrow[p][j * 256 + ((kb * 64 + g * 16) ^ ((j & 7) << 4))]);
                bias = __builtin_amdgcn_mfma_f32_16x16x32_bf16(wzf[kb], bz, bias, 0, 0, 0);
            }
            #pragma unroll
            for (int r = 0; r < 4; ++r) {
                int h = g * 4 + r;
                float ex = (h < 12) ? sx[((size_t)i * 12 + h) * 768 + j0 + j] : 0.f;
                float att = bias[r] + ex;
                attf[h][j] = att;
                ushort hi = f2bu(att);
                *(ushort*)(&attbh[h * 80 + j * 2]) = hi;
                *(ushort*)(&attbl[h * 80 + j * 2]) = f2bu(att - bu2f(hi));
            }
        }
        __syncthreads();
        // ---- phase B ----
        {   // o1T MFMA: wave owns d-blocks {2wv, 2wv+1}; hi + lo accumulate
            short8v bh = *(const short8v*)(&attbh[lm * 80 + g * 16]);
            short8v bl = *(const short8v*)(&attbl[lm * 80 + g * 16]);
            #pragma unroll
            for (int q = 0; q < 2; ++q) {
                int d = (wv * 2 + q) * 16 + lm;
                short8v az = *(const short8v*)(
                    &zT[p][d * 64 + ((g * 16) ^ (((d >> 2) & 3) << 4))]);
                acc1[q] = __builtin_amdgcn_mfma_f32_16x16x32_bf16(az, bh, acc1[q], 0, 0, 0);
                acc1[q] = __builtin_amdgcn_mfma_f32_16x16x32_bf16(az, bl, acc1[q], 0, 0, 0);
            }
        }
        if (tid < 192) {  // o2: fp32 att
            #pragma unroll
            for (int jj = 0; jj < 32; ++jj)
                acc2 += attf[h2][jj] * lin[(size_t)(j0 + jj) * NLIN + 384 + tid];
        }
        if (tid < 216) {  // o3: fp32 att
            #pragma unroll
            for (int jj = 0; jj < 32; ++jj)
                acc3 += attf[h3][jj] * v3g[(size_t)(j0 + jj) * 216 + tid];
        }
        if (t < 23) {
            #pragma unroll
            for (int s = 0; s < 4; ++s) {
                int k4 = s * 256 + tid, j = k4 >> 5, d0 = (k4 & 31) * 4;
                float4 v = zreg[s];
                ushort b0 = f2bu(v.x), b1 = f2bu(v.y), b2 = f2bu(v.z), b3 = f2bu(v.w);
                uint32_t lo = b0 | ((uint32_t)b1 << 16), hi = b2 | ((uint32_t)b3 << 16);
                *(uint64_t*)(&zrow[p ^ 1][j * 256 + ((d0 * 2) ^ ((j & 7) << 4))]) =
                    (uint64_t)lo | ((uint64_t)hi << 32);
                ushort bs[4] = {b0, b1, b2, b3};
                #pragma unroll
                for (int m = 0; m < 4; ++m) {
                    int d = d0 + m;
                    *(ushort*)(&zT[p ^ 1][d * 64 + ((j * 2) ^ (((d >> 2) & 3) << 4))]) = bs[m];
                }
            }
        }
        __syncthreads();
        p ^= 1;
    }
    // epilogue
    if (lm < 12) {
        #pragma unroll
        for (int q = 0; q < 2; ++q) {
            int mb = wv * 2 + q;
            #pragma unroll
            for (int r = 0; r < 4; ++r)
                o1[(size_t)i * 1536 + lm * 128 + mb * 16 + g * 4 + r] = acc1[q][r];
        }
    }
    if (tid < 192) o2[(size_t)i * 192 + tid] = acc2;
    if (tid < 216) o3s[tid] = acc3;
    __syncthreads();
    if (tid < 72) {
        float x0 = o3s[tid * 3 + 0] - trans[i * 3 + 0];
        float x1 = o3s[tid * 3 + 1] - trans[i * 3 + 1];
        float x2 = o3s[tid * 3 + 2] - trans[i * 3 + 2];
        const float* R = &rot[(size_t)i * 9];
        o3l[(size_t)i * 216 + tid * 3 + 0] = R[0]*x0 + R[3]*x1 + R[6]*x2;
        o3l[(size_t)i * 216 + tid * 3 + 1] = R[1]*x0 + R[4]*x1 + R[7]*x2;
        o3l[(size_t)i * 216 + tid * 3 + 2] = R[2]*x0 + R[5]*x1 + R[8]*x2;
    }
}

// ---------------------------------------------------------------------------
// Kernel 5: partial output projection. [768,1944]@[1944,384]
// ---------------------------------------------------------------------------
#define KCH 324
__global__ __launch_bounds__(384) void proj_kernel(
    const float* __restrict__ o1, const float* __restrict__ o2,
    const float* __restrict__ o3l,
    const float* __restrict__ W1, const float* __restrict__ W2,
    const float* __restrict__ W3,
    float* __restrict__ part)
{
    const int it = blockIdx.x, kt = blockIdx.y;
    const int tid = threadIdx.x;
    const int kbeg = kt * KCH, kend = kbeg + KCH;
    __shared__ float olds[8][KCH];
    for (int idx = tid; idx < 8 * KCH; idx += 384) {
        int r = idx / KCH, kk = idx % KCH;
        int k = kbeg + kk;
        int i = it * 8 + r;
        float v;
        if (k < 1536)      v = o1[(size_t)i * 1536 + k];
        else if (k < 1728) v = o2[(size_t)i * 192 + k - 1536];
        else               v = o3l[(size_t)i * 216 + k - 1728];
        olds[r][kk] = v;
    }
    __syncthreads();
    float acc[8] = {};
    {
        int s0 = kbeg, s1 = (kend < 1536) ? kend : 1536;
        for (int k = s0; k < s1; ++k) {
            float w = W1[(size_t)k * 384 + tid];
            int kk = k - kbeg;
            #pragma unroll
            for (int r = 0; r < 8; ++r) acc[r] += olds[r][kk] * w;
        }
    }
    {
        int s0 = (kbeg > 1536) ? kbeg : 1536, s1 = (kend < 1728) ? kend : 1728;
        for (int k = s0; k < s1; ++k) {
            float w = W2[(size_t)(k - 1536) * 384 + tid];
            int kk = k - kbeg;
            #pragma unroll
            for (int r = 0; r < 8; ++r) acc[r] += olds[r][kk] * w;
        }
    }
    {
        int s0 = (kbeg > 1728) ? kbeg : 1728, s1 = kend;
        for (int k = s0; k < s1; ++k) {
            float w = W3[(size_t)(k - 1728) * 384 + tid];
            int kk = k - kbeg;
            #pragma unroll
            for (int r = 0; r < 8; ++r) acc[r] += olds[r][kk] * w;
        }
    }
    for (int r = 0; r < 8; ++r)
        part[((size_t)kt * LL + it * 8 + r) * 384 + tid] = acc[r];
}

// ---------------------------------------------------------------------------
// Kernel 6: reduce partials + biases
// ---------------------------------------------------------------------------
__global__ __launch_bounds__(256) void final_kernel(
    const float* __restrict__ part,
    const float* __restrict__ b1, const float* __restrict__ b2,
    const float* __restrict__ b3, float* __restrict__ out)
{
    int idx = blockIdx.x * 256 + threadIdx.x;
    if (idx < LL * 384) {
        int n = idx % 384;
        float v = b1[n] + b2[n] + b3[n];
        #pragma unroll
        for (int kt = 0; kt < 6; ++kt) v += part[(size_t)kt * 294912 + idx];
        out[idx] = v;
    }
}

extern "C" void kernel_launch(void* const* d_in, const int* in_sizes, int n_in,
                              void* d_out, int out_size, void* d_ws, size_t ws_size,
                              hipStream_t stream) {
    const float* s     = (const float*)d_in[0];
    const float* z     = (const float*)d_in[1];
    const float* rot   = (const float*)d_in[2];
    const float* trans = (const float*)d_in[3];
    const float* Wq1   = (const float*)d_in[4];
    const float* Wk1   = (const float*)d_in[5];
    const float* Wv1   = (const float*)d_in[6];
    const float* Wq2   = (const float*)d_in[7];
    const float* Wk2   = (const float*)d_in[8];
    const float* Wv3   = (const float*)d_in[9];
    const float* Wz    = (const float*)d_in[10];
    const float* W1    = (const float*)d_in[11];
    const float* b1    = (const float*)d_in[12];
    const float* W2    = (const float*)d_in[13];
    const float* b2    = (const float*)d_in[14];
    const float* W3    = (const float*)d_in[15];
    const float* b3    = (const float*)d_in[16];
    const float* gamma = (const float*)d_in[17];
    float* ws  = (float*)d_ws;
    float* out = (float*)d_out;

    float*  lin  = ws + OFF_LIN;
    float*  v3g  = ws + OFF_V3G;
    ushort* qbh  = (ushort*)(ws + OFF_QBH);
    ushort* kbh  = (ushort*)(ws + OFF_KBH);
    ushort* qbl  = (ushort*)(ws + OFF_QBL);
    ushort* kbl  = (ushort*)(ws + OFF_KBL);
    ushort* wzp  = (ushort*)(ws + OFF_WZ);
    float*  sqwh = ws + OFF_SQWH;
    float*  skwh = ws + OFF_SKWH;
    float*  sx   = ws + OFF_SX;
    float*  o1   = ws + OFF_O1;
    float*  o2   = ws + OFF_O2;
    float*  o3l  = ws + OFF_O3;
    float*  part = ws + OFF_SX;   // alias: sx dead before proj runs

    dim3 gA(17, 12);
    gemm_lin_kernel<<<gA, 256, 0, stream>>>(s, Wq1, Wk1, Wv1, Wq2, Wk2, Wv3, lin);
    transform_kernel<<<LL, 192, 0, stream>>>(lin, rot, trans, gamma, Wz,
                                             v3g, qbh, qbl, kbh, kbl, wzp,
                                             sqwh, skwh);
    dim3 gS(48, 12);
    sextra_kernel<<<gS, 256, 0, stream>>>(qbh, qbl, kbh, kbl, sqwh, skwh, sx);
    attn_kernel<<<LL, 256, 0, stream>>>(z, lin, v3g, sx, wzp, rot, trans,
                                        o1, o2, o3l);
    dim3 gC(96, 6);
    proj_kernel<<<gC, 384, 0, stream>>>(o1, o2, o3l, W1, W2, W3, part);
    final_kernel<<<(LL * 384 + 255) / 256, 256, 0, stream>>>(part, b1, b2, b3, out);
}

// Round 6
// 324.102 us; speedup vs baseline: 1.2497x; 1.2497x over previous
//
#include <hip/hip_runtime.h>
#include <math.h>
#include <stdint.h>

// Problem constants
#define LL 768
#define DIN 384
#define HH 12
#define NLIN 1080          // 192*3 + 144*2 + 216
#define WC_HALF 0.11785113019775792f   // 0.5*sqrt(2/36)
#define C_SQU 0.25f

// Workspace layout (float units)
#define OFF_LIN    0u          // 829440
#define OFF_V1P    829440u     // 73728  (ushort 768*192, j-pair packed)
#define OFF_V3P    903168u     // 82944  (ushort 768*216, j-pair packed)
#define OFF_QBH    986112u     // 147456 (bf16 768*12*32)
#define OFF_QBL    1133568u    // 147456
#define OFF_KBH    1281024u    // 147456
#define OFF_KBL    1428480u    // 147456
#define OFF_WZ     1575936u    // 1024   (bf16 4*64*8)
#define OFF_SQWH   1576960u    // 9216
#define OFF_SKWH   1586176u    // 9216
#define OFF_SX     1595392u    // 7077888 fp32 (part[] aliases here later)
#define OFF_O1     8673280u    // 1179648
#define OFF_O2     9852928u    // 147456
#define OFF_O3     10000384u   // 165888
// end: 10166272 floats = 40.7 MB

typedef __attribute__((ext_vector_type(8))) short short8v;
typedef __attribute__((ext_vector_type(4))) float float4v;

__device__ __forceinline__ ushort f2bu(float f) {
    union { float f; uint32_t u; } v; v.f = f;
    uint32_t r = (v.u + 0x7FFFu + ((v.u >> 16) & 1u)) >> 16;
    return (ushort)r;
}
__device__ __forceinline__ float bu2f(ushort u) {
    union { uint32_t u; float f; } v; v.u = ((uint32_t)u) << 16; return v.f;
}
__device__ __forceinline__ float blo2f(uint32_t u) {
    union { uint32_t u; float f; } v; v.u = u << 16; return v.f;
}
__device__ __forceinline__ float bhi2f(uint32_t u) {
    union { uint32_t u; float f; } v; v.u = u & 0xFFFF0000u; return v.f;
}

// ---------------------------------------------------------------------------
// Kernel 1: lin = s @ [Wq1|Wk1|Wv1|Wq2|Wk2|Wv3]   ([768,384]@[384,1080])
// ---------------------------------------------------------------------------
__global__ __launch_bounds__(256) void gemm_lin_kernel(
    const float* __restrict__ s,
    const float* __restrict__ Wq1, const float* __restrict__ Wk1,
    const float* __restrict__ Wv1, const float* __restrict__ Wq2,
    const float* __restrict__ Wk2, const float* __restrict__ Wv3,
    float* __restrict__ lin)
{
    const int n0 = blockIdx.x * 64;
    const int i0 = blockIdx.y * 64;
    const int tid = threadIdx.x;
    __shared__ float sT[64][17];
    __shared__ float wT[16][65];
    const int tc = tid & 15, tr = tid >> 4;
    float acc[4][4] = {};
    for (int k0 = 0; k0 < DIN; k0 += 16) {
        __syncthreads();
        for (int idx = tid; idx < 1024; idx += 256) {
            int r = idx >> 4, kk = idx & 15;
            sT[r][kk] = s[(size_t)(i0 + r) * DIN + k0 + kk];
        }
        for (int idx = tid; idx < 1024; idx += 256) {
            int kk = idx >> 6, c = idx & 63;
            int col = n0 + c;
            float v = 0.f;
            if (col < NLIN) {
                const float* W; int nout, cc2;
                if      (col < 192) { W = Wq1; nout = 192; cc2 = col; }
                else if (col < 384) { W = Wk1; nout = 192; cc2 = col - 192; }
                else if (col < 576) { W = Wv1; nout = 192; cc2 = col - 384; }
                else if (col < 720) { W = Wq2; nout = 144; cc2 = col - 576; }
                else if (col < 864) { W = Wk2; nout = 144; cc2 = col - 720; }
                else                { W = Wv3; nout = 216; cc2 = col - 864; }
                v = W[(size_t)(k0 + kk) * nout + cc2];
            }
            wT[kk][c] = v;
        }
        __syncthreads();
        #pragma unroll
        for (int kk = 0; kk < 16; ++kk) {
            float a[4], b[4];
            #pragma unroll
            for (int r = 0; r < 4; ++r) a[r] = sT[tr * 4 + r][kk];
            #pragma unroll
            for (int c = 0; c < 4; ++c) b[c] = wT[kk][tc * 4 + c];
            #pragma unroll
            for (int r = 0; r < 4; ++r)
                #pragma unroll
                for (int c = 0; c < 4; ++c) acc[r][c] += a[r] * b[c];
        }
    }
    for (int r = 0; r < 4; ++r)
        for (int c = 0; c < 4; ++c) {
            int col = n0 + tc * 4 + c;
            if (col < NLIN)
                lin[(size_t)(i0 + tr * 4 + r) * NLIN + col] = acc[r][c];
        }
}

// ---------------------------------------------------------------------------
// Kernel 2: transforms -> hi/lo bf16 bundles, j-pair-packed bf16 v1p/v3p,
// fp32 sqwh/skwh, Wz A-frag pack.
// ---------------------------------------------------------------------------
__global__ __launch_bounds__(192) void transform_kernel(
    const float* __restrict__ lin, const float* __restrict__ rot,
    const float* __restrict__ trans, const float* __restrict__ gamma,
    const float* __restrict__ Wz,
    ushort* __restrict__ v1p, ushort* __restrict__ v3p,
    ushort* __restrict__ qbh, ushort* __restrict__ qbl,
    ushort* __restrict__ kbh, ushort* __restrict__ kbl,
    ushort* __restrict__ wzpack,
    float* __restrict__ sqwh, float* __restrict__ skwh)
{
    const int l = blockIdx.x;
    const int tid = threadIdx.x;
    __shared__ float q2s[144], k2s[144], sqp[48], skp[48];
    __shared__ float whs[12];
    __shared__ float R[9], T[3];
    if (tid < 9) R[tid] = rot[l * 9 + tid];
    if (tid >= 9 && tid < 12) T[tid - 9] = trans[l * 3 + tid - 9];
    __syncthreads();
    if (tid < 48) {
        const float* x = &lin[(size_t)l * NLIN + 576 + tid * 3];
        float x0 = x[0], x1 = x[1], x2 = x[2], ss = 0.f;
        #pragma unroll
        for (int i2 = 0; i2 < 3; ++i2) {
            float v = R[i2*3+0]*x0 + R[i2*3+1]*x1 + R[i2*3+2]*x2 + T[i2];
            q2s[tid * 3 + i2] = v; ss += v * v;
        }
        sqp[tid] = ss;
    } else if (tid < 96) {
        int t2 = tid - 48;
        const float* x = &lin[(size_t)l * NLIN + 720 + t2 * 3];
        float x0 = x[0], x1 = x[1], x2 = x[2], ss = 0.f;
        #pragma unroll
        for (int i2 = 0; i2 < 3; ++i2) {
            float v = R[i2*3+0]*x0 + R[i2*3+1]*x1 + R[i2*3+2]*x2 + T[i2];
            k2s[t2 * 3 + i2] = v; ss += v * v;
        }
        skp[t2] = ss;
    } else if (tid < 168) {
        int t2 = tid - 96;
        const float* x = &lin[(size_t)l * NLIN + 864 + t2 * 3];
        float x0 = x[0], x1 = x[1], x2 = x[2];
        #pragma unroll
        for (int i2 = 0; i2 < 3; ++i2) {
            float v = R[i2*3+0]*x0 + R[i2*3+1]*x1 + R[i2*3+2]*x2 + T[i2];
            // v3 global points, bf16, j-pair packed: v3p[l/2][idx][l&1]
            v3p[(size_t)(l >> 1) * 432 + (t2 * 3 + i2) * 2 + (l & 1)] = f2bu(v);
        }
    }
    __syncthreads();
    if (tid < 12) {
        float sq = sqp[tid*4] + sqp[tid*4+1] + sqp[tid*4+2] + sqp[tid*4+3];
        float sk = skp[tid*4] + skp[tid*4+1] + skp[tid*4+2] + skp[tid*4+3];
        float w = logf(1.0f + expf(gamma[tid])) * WC_HALF;
        whs[tid] = w;
        sqwh[l * 12 + tid] = w * sq;   // fp32, exact path
        skwh[l * 12 + tid] = w * sk;
    }
    __syncthreads();
    // v1 (lin cols 384..575) bf16, j-pair packed
    if (tid < 192)
        v1p[(size_t)(l >> 1) * 384 + tid * 2 + (l & 1)] =
            f2bu(lin[(size_t)l * NLIN + 384 + tid]);
    for (int idx = tid; idx < 384; idx += 192) {
        int h = idx >> 5, k = idx & 31;
        float qv, kv;
        if (k < 16) {
            qv = lin[(size_t)l * NLIN + h * 16 + k];
            kv = C_SQU * lin[(size_t)l * NLIN + 192 + h * 16 + k];
        } else if (k < 28) {
            int u = k - 16;
            qv = q2s[h * 12 + u];
            kv = 2.0f * whs[h] * k2s[h * 12 + u];
        } else { qv = 0.0f; kv = 0.0f; }
        size_t base = (size_t)l * 384 + idx;
        ushort qh = f2bu(qv), kh = f2bu(kv);
        qbh[base] = qh; qbl[base] = f2bu(qv - bu2f(qh));
        kbh[base] = kh; kbl[base] = f2bu(kv - bu2f(kh));
    }
    if (l == 0) {  // wzpack[kb][lane][e] = Wz[kb*32+(lane>>4)*8+e][lane&15]
        for (int idx = tid; idx < 2048; idx += 192) {
            int kb = idx >> 9, lane = (idx >> 3) & 63, e = idx & 7;
            int d = kb * 32 + (lane >> 4) * 8 + e, h = lane & 15;
            wzpack[idx] = (h < 12) ? f2bu(Wz[d * 12 + h]) : (ushort)0;
        }
    }
}

// ---------------------------------------------------------------------------
// Kernel 3: sx[i][h][j] = hi/lo-dot(qb,kb) - sqwh[i,h] - skwh[j,h] (fp32)
// ---------------------------------------------------------------------------
__global__ __launch_bounds__(256) void sextra_kernel(
    const ushort* __restrict__ qbh, const ushort* __restrict__ qbl,
    const ushort* __restrict__ kbh, const ushort* __restrict__ kbl,
    const float* __restrict__ sqwh, const float* __restrict__ skwh,
    float* __restrict__ sx)
{
    const int tid = threadIdx.x;
    const int wv = tid >> 6, lane = tid & 63, lm = lane & 15, g = lane >> 4;
    const int i0 = blockIdx.x * 16;
    const int jb = blockIdx.y * 64 + wv * 16;
    for (int h = 0; h < 12; ++h) {
        size_t qoff = ((size_t)(i0 + lm) * 12 + h) * 32 + g * 8;
        size_t koff = ((size_t)(jb + lm) * 12 + h) * 32 + g * 8;
        short8v ah = *(const short8v*)(qbh + qoff);
        short8v al = *(const short8v*)(qbl + qoff);
        short8v bh = *(const short8v*)(kbh + koff);
        short8v bl = *(const short8v*)(kbl + koff);
        float4v c = {0.f, 0.f, 0.f, 0.f};
        c = __builtin_amdgcn_mfma_f32_16x16x32_bf16(ah, bh, c, 0, 0, 0);
        c = __builtin_amdgcn_mfma_f32_16x16x32_bf16(ah, bl, c, 0, 0, 0);
        c = __builtin_amdgcn_mfma_f32_16x16x32_bf16(al, bh, c, 0, 0, 0);
        float skv = skwh[(jb + lm) * 12 + h];
        #pragma unroll
        for (int r = 0; r < 4; ++r) {
            int ii = i0 + g * 4 + r;
            sx[((size_t)ii * 12 + h) * 768 + jb + lm] =
                c[r] - sqwh[ii * 12 + h] - skv;
        }
    }
}

// ---------------------------------------------------------------------------
// Kernel 4: fused attention. One block per query row i. zrow-only LDS
// (XOR-swizzled); o1 B-frags via column b16 reads (no zT). v1/v3/sx
// register-prefetched. 2 barriers/tile.
// ---------------------------------------------------------------------------
__global__ __launch_bounds__(256) void attn_kernel(
    const float* __restrict__ z, const ushort* __restrict__ v1p,
    const ushort* __restrict__ v3p, const float* __restrict__ sx,
    const ushort* __restrict__ wzp,
    const float* __restrict__ rot, const float* __restrict__ trans,
    float* __restrict__ o1, float* __restrict__ o2, float* __restrict__ o3l)
{
    const int i = blockIdx.x, tid = threadIdx.x;
    const int wv = tid >> 6, lane = tid & 63, lm = lane & 15, g = lane >> 4;
    __shared__ __attribute__((aligned(16))) char zrow[2][32 * 256]; // [j][d] bf16, swz ^((j&7)<<4)
    __shared__ __attribute__((aligned(16))) char attbh[16 * 80];    // hi bf16 [h][j]
    __shared__ __attribute__((aligned(16))) char attbl[16 * 80];    // lo bf16 [h][j]
    __shared__ float attf[16][33];                                  // fp32 [h][j]
    __shared__ float o3s[216];

    short8v wzf[4];
    #pragma unroll
    for (int kb = 0; kb < 4; ++kb)
        wzf[kb] = *(const short8v*)(wzp + (kb * 64 + lane) * 8);

    const float4* zsrc = (const float4*)(z + (size_t)i * (LL * 128));
    const int jA = wv * 16 + lm;   // phase-A j (waves 0/1)
    const int h2 = tid >> 4;       // o2 head (tid<192)
    const int h3 = tid / 18;       // o3 head (tid<216)

    // ---- prologue: tile 0 ----
    {
        float4 z0[4];
        #pragma unroll
        for (int s = 0; s < 4; ++s) z0[s] = zsrc[s * 256 + tid];
        #pragma unroll
        for (int s = 0; s < 4; ++s) {
            int k4 = s * 256 + tid, j = k4 >> 5, d0 = (k4 & 31) * 4;
            float4 v = z0[s];
            ushort b0 = f2bu(v.x), b1 = f2bu(v.y), b2 = f2bu(v.z), b3 = f2bu(v.w);
            uint32_t lo = b0 | ((uint32_t)b1 << 16), hi = b2 | ((uint32_t)b3 << 16);
            *(uint64_t*)(&zrow[0][j * 256 + ((d0 * 2) ^ ((j & 7) << 4))]) =
                (uint64_t)lo | ((uint64_t)hi << 32);
        }
    }
    float sxr[4] = {0.f, 0.f, 0.f, 0.f};
    if (wv < 2 && g < 3) {
        #pragma unroll
        for (int r = 0; r < 4; ++r)
            sxr[r] = sx[((size_t)i * 12 + g * 4 + r) * 768 + jA];
    }
    __syncthreads();

    float4v acc1[2] = {{0.f,0.f,0.f,0.f}, {0.f,0.f,0.f,0.f}};
    float acc2 = 0.f, acc3 = 0.f;
    int p = 0;

    for (int t = 0; t < 24; ++t) {
        const int j0 = t * 32;
        // ---- issue global loads (prefetch) ----
        float4 zreg[4];
        if (t < 23) {
            #pragma unroll
            for (int s = 0; s < 4; ++s)
                zreg[s] = zsrc[(size_t)(t + 1) * 1024 + s * 256 + tid];
        }
        uint v1u[16], v3u[16];
        if (tid < 192) {
            #pragma unroll
            for (int jp = 0; jp < 16; ++jp)
                v1u[jp] = *(const uint*)(v1p + ((size_t)(t * 16 + jp)) * 384 + tid * 2);
        }
        if (tid < 216) {
            #pragma unroll
            for (int jp = 0; jp < 16; ++jp)
                v3u[jp] = *(const uint*)(v3p + ((size_t)(t * 16 + jp)) * 432 + tid * 2);
        }
        float sxn[4] = {0.f, 0.f, 0.f, 0.f};
        if (wv < 2 && g < 3 && t < 23) {
            #pragma unroll
            for (int r = 0; r < 4; ++r)
                sxn[r] = sx[((size_t)i * 12 + g * 4 + r) * 768 + j0 + 32 + jA];
        }
        // ---- phase A: waves 0/1 produce att tile ----
        if (wv < 2) {
            float4v bias = {0.f, 0.f, 0.f, 0.f};
            #pragma unroll
            for (int kb = 0; kb < 4; ++kb) {
                short8v bz = *(const short8v*)(
                    &zrow[p][jA * 256 + ((kb * 64 + g * 16) ^ ((jA & 7) << 4))]);
                bias = __builtin_amdgcn_mfma_f32_16x16x32_bf16(wzf[kb], bz, bias, 0, 0, 0);
            }
            #pragma unroll
            for (int r = 0; r < 4; ++r) {
                int h = g * 4 + r;
                float att = bias[r] + sxr[r];
                attf[h][jA] = att;
                ushort hi = f2bu(att);
                *(ushort*)(&attbh[h * 80 + jA * 2]) = hi;
                *(ushort*)(&attbl[h * 80 + jA * 2]) = f2bu(att - bu2f(hi));
            }
        }
        __syncthreads();
        // ---- phase B ----
        {   // o1 MFMA: D[h][d'] = att[h][jj] x z[jj][d'];  B via column b16 reads
            short8v ah = *(const short8v*)(&attbh[lm * 80 + g * 16]);
            short8v al = *(const short8v*)(&attbl[lm * 80 + g * 16]);
            #pragma unroll
            for (int q = 0; q < 2; ++q) {
                const int b = wv * 2 + q;
                short8v bf;
                #pragma unroll
                for (int e = 0; e < 8; ++e) {
                    int jj = g * 8 + e;
                    bf[e] = *(const short*)(&zrow[p][jj * 256 +
                              (((b * 16 + lm) * 2) ^ ((jj & 7) << 4))]);
                }
                acc1[q] = __builtin_amdgcn_mfma_f32_16x16x32_bf16(ah, bf, acc1[q], 0, 0, 0);
                acc1[q] = __builtin_amdgcn_mfma_f32_16x16x32_bf16(al, bf, acc1[q], 0, 0, 0);
            }
        }
        if (tid < 192) {  // o2: fp32 att x prefetched bf16 v1 pairs
            #pragma unroll
            for (int jp = 0; jp < 16; ++jp) {
                uint u = v1u[jp];
                acc2 += attf[h2][2 * jp] * blo2f(u)
                      + attf[h2][2 * jp + 1] * bhi2f(u);
            }
        }
        if (tid < 216) {  // o3
            #pragma unroll
            for (int jp = 0; jp < 16; ++jp) {
                uint u = v3u[jp];
                acc3 += attf[h3][2 * jp] * blo2f(u)
                      + attf[h3][2 * jp + 1] * bhi2f(u);
            }
        }
        // ---- stage next tile ----
        if (t < 23) {
            #pragma unroll
            for (int s = 0; s < 4; ++s) {
                int k4 = s * 256 + tid, j = k4 >> 5, d0 = (k4 & 31) * 4;
                float4 v = zreg[s];
                ushort b0 = f2bu(v.x), b1 = f2bu(v.y), b2 = f2bu(v.z), b3 = f2bu(v.w);
                uint32_t lo = b0 | ((uint32_t)b1 << 16), hi = b2 | ((uint32_t)b3 << 16);
                *(uint64_t*)(&zrow[p ^ 1][j * 256 + ((d0 * 2) ^ ((j & 7) << 4))]) =
                    (uint64_t)lo | ((uint64_t)hi << 32);
            }
        }
        __syncthreads();
        #pragma unroll
        for (int r = 0; r < 4; ++r) sxr[r] = sxn[r];
        p ^= 1;
    }
    // epilogue: D[h=g*4+r][d=b*16+lm]
    if (g < 3) {
        #pragma unroll
        for (int q = 0; q < 2; ++q) {
            const int b = wv * 2 + q;
            #pragma unroll
            for (int r = 0; r < 4; ++r)
                o1[(size_t)i * 1536 + (g * 4 + r) * 128 + b * 16 + lm] = acc1[q][r];
        }
    }
    if (tid < 192) o2[(size_t)i * 192 + tid] = acc2;
    if (tid < 216) o3s[tid] = acc3;
    __syncthreads();
    if (tid < 72) {
        float x0 = o3s[tid * 3 + 0] - trans[i * 3 + 0];
        float x1 = o3s[tid * 3 + 1] - trans[i * 3 + 1];
        float x2 = o3s[tid * 3 + 2] - trans[i * 3 + 2];
        const float* R = &rot[(size_t)i * 9];
        o3l[(size_t)i * 216 + tid * 3 + 0] = R[0]*x0 + R[3]*x1 + R[6]*x2;
        o3l[(size_t)i * 216 + tid * 3 + 1] = R[1]*x0 + R[4]*x1 + R[7]*x2;
        o3l[(size_t)i * 216 + tid * 3 + 2] = R[2]*x0 + R[5]*x1 + R[8]*x2;
    }
}

// ---------------------------------------------------------------------------
// Kernel 5: partial output projection. [768,1944]@[1944,384]
// 16 rows/block, 6 K-chunks of 324.
// ---------------------------------------------------------------------------
#define KCH 324
__global__ __launch_bounds__(384) void proj_kernel(
    const float* __restrict__ o1, const float* __restrict__ o2,
    const float* __restrict__ o3l,
    const float* __restrict__ W1, const float* __restrict__ W2,
    const float* __restrict__ W3,
    float* __restrict__ part)
{
    const int it = blockIdx.x, kt = blockIdx.y;
    const int tid = threadIdx.x;
    const int kbeg = kt * KCH, kend = kbeg + KCH;
    __shared__ float olds[16][KCH];
    for (int idx = tid; idx < 16 * KCH; idx += 384) {
        int r = idx / KCH, kk = idx % KCH;
        int k = kbeg + kk;
        int i = it * 16 + r;
        float v;
        if (k < 1536)      v = o1[(size_t)i * 1536 + k];
        else if (k < 1728) v = o2[(size_t)i * 192 + k - 1536];
        else               v = o3l[(size_t)i * 216 + k - 1728];
        olds[r][kk] = v;
    }
    __syncthreads();
    float acc[16] = {};
    {
        int s0 = kbeg, s1 = (kend < 1536) ? kend : 1536;
        for (int k = s0; k < s1; ++k) {
            float w = W1[(size_t)k * 384 + tid];
            int kk = k - kbeg;
            #pragma unroll
            for (int r = 0; r < 16; ++r) acc[r] += olds[r][kk] * w;
        }
    }
    {
        int s0 = (kbeg > 1536) ? kbeg : 1536, s1 = (kend < 1728) ? kend : 1728;
        for (int k = s0; k < s1; ++k) {
            float w = W2[(size_t)(k - 1536) * 384 + tid];
            int kk = k - kbeg;
            #pragma unroll
            for (int r = 0; r < 16; ++r) acc[r] += olds[r][kk] * w;
        }
    }
    {
        int s0 = (kbeg > 1728) ? kbeg : 1728, s1 = kend;
        for (int k = s0; k < s1; ++k) {
            float w = W3[(size_t)(k - 1728) * 384 + tid];
            int kk = k - kbeg;
            #pragma unroll
            for (int r = 0; r < 16; ++r) acc[r] += olds[r][kk] * w;
        }
    }
    for (int r = 0; r < 16; ++r)
        part[((size_t)kt * LL + it * 16 + r) * 384 + tid] = acc[r];
}

// ---------------------------------------------------------------------------
// Kernel 6: reduce partials + biases
// ---------------------------------------------------------------------------
__global__ __launch_bounds__(256) void final_kernel(
    const float* __restrict__ part,
    const float* __restrict__ b1, const float* __restrict__ b2,
    const float* __restrict__ b3, float* __restrict__ out)
{
    int idx = blockIdx.x * 256 + threadIdx.x;
    if (idx < LL * 384) {
        int n = idx % 384;
        float v = b1[n] + b2[n] + b3[n];
        #pragma unroll
        for (int kt = 0; kt < 6; ++kt) v += part[(size_t)kt * 294912 + idx];
        out[idx] = v;
    }
}

extern "C" void kernel_launch(void* const* d_in, const int* in_sizes, int n_in,
                              void* d_out, int out_size, void* d_ws, size_t ws_size,
                              hipStream_t stream) {
    const float* s     = (const float*)d_in[0];
    const float* z     = (const float*)d_in[1];
    const float* rot   = (const float*)d_in[2];
    const float* trans = (const float*)d_in[3];
    const float* Wq1   = (const float*)d_in[4];
    const float* Wk1   = (const float*)d_in[5];
    const float* Wv1   = (const float*)d_in[6];
    const float* Wq2   = (const float*)d_in[7];
    const float* Wk2   = (const float*)d_in[8];
    const float* Wv3   = (const float*)d_in[9];
    const float* Wz    = (const float*)d_in[10];
    const float* W1    = (const float*)d_in[11];
    const float* b1    = (const float*)d_in[12];
    const float* W2    = (const float*)d_in[13];
    const float* b2    = (const float*)d_in[14];
    const float* W3    = (const float*)d_in[15];
    const float* b3    = (const float*)d_in[16];
    const float* gamma = (const float*)d_in[17];
    float* ws  = (float*)d_ws;
    float* out = (float*)d_out;

    float*  lin  = ws + OFF_LIN;
    ushort* v1p  = (ushort*)(ws + OFF_V1P);
    ushort* v3p  = (ushort*)(ws + OFF_V3P);
    ushort* qbh  = (ushort*)(ws + OFF_QBH);
    ushort* qbl  = (ushort*)(ws + OFF_QBL);
    ushort* kbh  = (ushort*)(ws + OFF_KBH);
    ushort* kbl  = (ushort*)(ws + OFF_KBL);
    ushort* wzp  = (ushort*)(ws + OFF_WZ);
    float*  sqwh = ws + OFF_SQWH;
    float*  skwh = ws + OFF_SKWH;
    float*  sx   = ws + OFF_SX;
    float*  o1   = ws + OFF_O1;
    float*  o2   = ws + OFF_O2;
    float*  o3l  = ws + OFF_O3;
    float*  part = ws + OFF_SX;   // alias: sx dead before proj runs

    dim3 gA(17, 12);
    gemm_lin_kernel<<<gA, 256, 0, stream>>>(s, Wq1, Wk1, Wv1, Wq2, Wk2, Wv3, lin);
    transform_kernel<<<LL, 192, 0, stream>>>(lin, rot, trans, gamma, Wz,
                                             v1p, v3p, qbh, qbl, kbh, kbl, wzp,
                                             sqwh, skwh);
    dim3 gS(48, 12);
    sextra_kernel<<<gS, 256, 0, stream>>>(qbh, qbl, kbh, kbl, sqwh, skwh, sx);
    attn_kernel<<<LL, 256, 0, stream>>>(z, v1p, v3p, sx, wzp, rot, trans,
                                        o1, o2, o3l);
    dim3 gC(48, 6);
    proj_kernel<<<gC, 384, 0, stream>>>(o1, o2, o3l, W1, W2, W3, part);
    final_kernel<<<(LL * 384 + 255) / 256, 256, 0, stream>>>(part, b1, b2, b3, out);
}